// Round 3
// baseline (182.427 us; speedup 1.0000x reference)
//
#include <hip/hip_runtime.h>
#include <math.h>

#define LFFT 16384
#define NTHREADS 1024
#define LDS_PITCH 17   // float2 per row (16 + 1 pad)

__device__ __forceinline__ float2 cadd(float2 a, float2 b){ return make_float2(a.x+b.x, a.y+b.y); }
__device__ __forceinline__ float2 csub(float2 a, float2 b){ return make_float2(a.x-b.x, a.y-b.y); }
__device__ __forceinline__ float2 cmul(float2 a, float2 b){ return make_float2(a.x*b.x - a.y*b.y, a.x*b.y + a.y*b.x); }

template<int S> __device__ __forceinline__ float2 mul_is(float2 a) {
    return make_float2(-(float)S * a.y, (float)S * a.x);
}

// Radix-4 butterfly. S=-1 fwd, S=+1 inverse (unnormalized).
template<int S> __device__ __forceinline__ void dft4_t(float2& a0, float2& a1, float2& a2, float2& a3) {
    float2 t0 = cadd(a0, a2);
    float2 t1 = csub(a0, a2);
    float2 t2 = cadd(a1, a3);
    float2 t3 = csub(a1, a3);
    a0 = cadd(t0, t2);
    a2 = csub(t0, t2);
    const float s = (float)S;
    a1 = make_float2(t1.x - s * t3.y, t1.y + s * t3.x);
    a3 = make_float2(t1.x + s * t3.y, t1.y - s * t3.x);
}

#define C16A 0.92387953251128675613f
#define C16B 0.70710678118654752440f
#define C16C 0.38268343236508977173f

// Fully-unrolled 16-point DFT, natural order in and out.
template<int S> __device__ __forceinline__ void dft16_t(float2 r[16]) {
    const float s = (float)S;
    const float2 w1 = make_float2( C16A, s * C16C);
    const float2 w2 = make_float2( C16B, s * C16B);
    const float2 w3 = make_float2( C16C, s * C16A);
    const float2 w6 = make_float2(-C16B, s * C16B);
    const float2 w9 = make_float2(-C16A, -s * C16C);
    float2 g[4][4];
    #pragma unroll
    for (int b = 0; b < 4; ++b) {
        float2 a0 = r[b], a1 = r[b+4], a2 = r[b+8], a3 = r[b+12];
        dft4_t<S>(a0, a1, a2, a3);
        g[b][0] = a0; g[b][1] = a1; g[b][2] = a2; g[b][3] = a3;
    }
    g[1][1] = cmul(g[1][1], w1);  g[1][2] = cmul(g[1][2], w2);  g[1][3] = cmul(g[1][3], w3);
    g[2][1] = cmul(g[2][1], w2);  g[2][2] = mul_is<S>(g[2][2]); g[2][3] = cmul(g[2][3], w6);
    g[3][1] = cmul(g[3][1], w3);  g[3][2] = cmul(g[3][2], w6);  g[3][3] = cmul(g[3][3], w9);
    #pragma unroll
    for (int ka = 0; ka < 4; ++ka) {
        float2 a0 = g[0][ka], a1 = g[1][ka], a2 = g[2][ka], a3 = g[3][ka];
        dft4_t<S>(a0, a1, a2, a3);
        r[ka] = a0; r[ka+4] = a1; r[ka+8] = a2; r[ka+12] = a3;
    }
}

// r[k] *= w^k, k = 1..15
__device__ __forceinline__ void twiddle15(float2 r[16], float2 w) {
    float2 w2 = cmul(w, w);
    float2 we = w2;
    float2 wo = cmul(w, w2);
    r[1] = cmul(r[1], w);
    r[2] = cmul(r[2], we);
    r[3] = cmul(r[3], wo);
    #pragma unroll
    for (int j = 2; j <= 7; ++j) {
        we = cmul(we, w2);  r[2*j]   = cmul(r[2*j],   we);
        wo = cmul(wo, w2);  r[2*j+1] = cmul(r[2*j+1], wo);
    }
}

// ---------------------------------------------------------------------------
// Evaluate S4 generating function K at root-of-unity index m (fp64 for the
// near-pole at m = L/2).
// ---------------------------------------------------------------------------
__device__ float2 evalK(int m, double step,
                        const float* __restrict__ Lr, const float* __restrict__ Li,
                        const float* __restrict__ Pr, const float* __restrict__ Pi,
                        const float* __restrict__ Br, const float* __restrict__ Bi,
                        const float* __restrict__ Cr, const float* __restrict__ Ci)
{
    double theta = (-2.0 * M_PI / (double)LFFT) * (double)m;
    double si, co;
    sincos(theta, &si, &co);
    double opr = 1.0 + co, opi = si;
    double omr = 1.0 - co, omi = -si;
    double iden = 1.0 / (opr*opr + opi*opi);
    double gs = 2.0 / step;
    double gr = gs * (omr*opr + omi*opi) * iden;
    double gi = gs * (omi*opr - omr*opi) * iden;
    double cr = 2.0 * opr * iden;
    double ci = -2.0 * opi * iden;

    double k00r=0,k00i=0,k01r=0,k01i=0,k10r=0,k10i=0,k11r=0,k11i=0;
    for (int n = 0; n < 64; ++n) {
        double dr = gr - (double)Lr[n];
        double di = gi - (double)Li[n];
        double id2 = 1.0 / (dr*dr + di*di);
        double vr =  dr * id2;
        double vi = -di * id2;
        double a0r = (double)Cr[n], a0i = -(double)Ci[n];
        double a1r = (double)Pr[n], a1i = -(double)Pi[n];
        double br  = (double)Br[n], bi  = (double)Bi[n];
        double pr  = (double)Pr[n], pi  = (double)Pi[n];
        double e00r = a0r*br - a0i*bi, e00i = a0r*bi + a0i*br;
        double e01r = a0r*pr - a0i*pi, e01i = a0r*pi + a0i*pr;
        double e10r = a1r*br - a1i*bi, e10i = a1r*bi + a1i*br;
        double e11r = a1r*pr - a1i*pi, e11i = a1r*pi + a1i*pr;
        k00r += vr*e00r - vi*e00i;  k00i += vr*e00i + vi*e00r;
        k01r += vr*e01r - vi*e01i;  k01i += vr*e01i + vi*e01r;
        k10r += vr*e10r - vi*e10i;  k10i += vr*e10i + vi*e10r;
        k11r += vr*e11r - vi*e11i;  k11i += vr*e11i + vi*e11r;
    }
    double rr = 1.0 + k11r, ri = k11i;
    double ir2 = 1.0 / (rr*rr + ri*ri);
    double qr0 = k01r*k10r - k01i*k10i;
    double qi0 = k01r*k10i + k01i*k10r;
    double qr = (qr0*rr + qi0*ri) * ir2;
    double qi = (qi0*rr - qr0*ri) * ir2;
    double sr = k00r - qr, sim = k00i - qi;
    return make_float2((float)(cr*sr - ci*sim), (float)(cr*sim + ci*sr));
}

// ---------------------------------------------------------------------------
// Kernel 1 (fused): twiddle table + Hermitian-symmetrized, 0.5/L-scaled
// kernel in the exact (thread, slot) order of the fft_conv multiply point:
//   p = t*16 + j ; m = k1 + 16*k3 + 256*(4*k5h + k5l) + 4096*k6
//   k1=t>>6, k3=(t>>2)&15, k5h=t&3, k5l=j>>2, k6=j&3
// ---------------------------------------------------------------------------
__global__ void s4_tables(const float* __restrict__ Lr, const float* __restrict__ Li,
                          const float* __restrict__ Pr, const float* __restrict__ Pi,
                          const float* __restrict__ Br, const float* __restrict__ Bi,
                          const float* __restrict__ Cr, const float* __restrict__ Ci,
                          const float* __restrict__ step_ptr,
                          float2* __restrict__ Kperm, float2* __restrict__ twid)
{
    int p = blockIdx.x * blockDim.x + threadIdx.x;
    if (p >= LFFT) return;
    double tth = (-2.0 * M_PI / (double)LFFT) * (double)p;
    double tsi, tco;
    sincos(tth, &tsi, &tco);
    twid[p] = make_float2((float)tco, (float)tsi);

    double step = (double)step_ptr[0];
    int t = p >> 4, j = p & 15;
    int k1 = t >> 6, k3 = (t >> 2) & 15, k5h = t & 3;
    int k5l = j >> 2, k6 = j & 3;
    int m = k1 + 16*k3 + 256*(4*k5h + k5l) + 4096*k6;
    float2 a = evalK(m, step, Lr, Li, Pr, Pi, Br, Bi, Cr, Ci);
    float2 b = evalK((LFFT - m) & (LFFT - 1), step, Lr, Li, Pr, Pi, Br, Bi, Cr, Ci);
    const float s = 0.5f / (float)LFFT;
    Kperm[p] = make_float2(s * (a.x + b.x), s * (a.y - b.y));
}

// ---------------------------------------------------------------------------
// Kernel 2: register-resident four-step FFT/IFFT, 16384 = 16 x 16 x 16 x 4.
// 1024 threads x 16 float2 in registers. LDS halved to 512 rows x 17
// (69.6 KiB -> 2 blocks/CU): each transpose runs in two row-phases,
// physical row = logical row & 511. Address patterns identical to the
// verified full-LDS version.
// ---------------------------------------------------------------------------
__global__ __launch_bounds__(NTHREADS, 8) void fft_conv(
    const float* __restrict__ x, float* __restrict__ y,
    const float2* __restrict__ twid, const float2* __restrict__ kperm)
{
    __shared__ float2 lds[512 * LDS_PITCH];   // 69,632 B
    const int t    = threadIdx.x;
    const int lane = t & 63;
    const int w    = t >> 6;        // 0..15
    const int l2   = t & 3;
    const int h    = (t >> 2) & 15; // lane>>2
    const bool lo  = (t < 512);
    const int tr   = t & 511;       // physical read row
    const size_t rowbase = (size_t)blockIdx.x * 2u * LFFT;
    const float* x0 = x + rowbase;
    const float* x1 = x0 + LFFT;

    float2 r[16];

    // ---- load: thread t owns n = t + 1024*a (coalesced) ----
    #pragma unroll
    for (int a = 0; a < 16; ++a)
        r[a] = make_float2(x0[t + NTHREADS*a], x1[t + NTHREADS*a]);

    // ---- P1: DFT-16 over a, twiddle W_16384^(t*k1) ----
    dft16_t<-1>(r);
    twiddle15(r, twid[t]);

    // ---- T1: r[k1] -> (row 64*k1 + lane, col w); read (row t, col a) ----
    {
        #pragma unroll
        for (int k = 0; k < 8; ++k)
            lds[(k*64 + lane) * LDS_PITCH + w] = r[k];
        __syncthreads();
        float2 tmp[16];
        if (lo) {
            #pragma unroll
            for (int a = 0; a < 16; ++a) tmp[a] = lds[tr * LDS_PITCH + a];
        }
        __syncthreads();
        #pragma unroll
        for (int k = 8; k < 16; ++k)
            lds[((k - 8)*64 + lane) * LDS_PITCH + w] = r[k];
        __syncthreads();
        if (!lo) {
            #pragma unroll
            for (int a = 0; a < 16; ++a) tmp[a] = lds[tr * LDS_PITCH + a];
        }
        __syncthreads();
        #pragma unroll
        for (int a = 0; a < 16; ++a) r[a] = tmp[a];
    }

    // ---- P2: DFT-16 over a2, twiddle W_1024^((t&63)*k3) ----
    dft16_t<-1>(r);
    twiddle15(r, twid[16 * lane]);

    // ---- T2: r[k3] -> (row w*64 + 4*k3 + l2, col h); read (row t, col a) ----
    {
        if (lo) {
            #pragma unroll
            for (int k = 0; k < 16; ++k)
                lds[(w*64 + 4*k + l2) * LDS_PITCH + h] = r[k];
        }
        __syncthreads();
        if (lo) {
            #pragma unroll
            for (int a = 0; a < 16; ++a) r[a] = lds[tr * LDS_PITCH + a];
        }
        __syncthreads();
        if (!lo) {
            #pragma unroll
            for (int k = 0; k < 16; ++k)
                lds[((w & 7)*64 + 4*k + l2) * LDS_PITCH + h] = r[k];
        }
        __syncthreads();
        if (!lo) {
            #pragma unroll
            for (int a = 0; a < 16; ++a) r[a] = lds[tr * LDS_PITCH + a];
        }
        __syncthreads();
    }

    // ---- P3: DFT-16 over a3, twiddle W_64^(l2*k5) ----
    dft16_t<-1>(r);
    twiddle15(r, twid[256 * l2]);

    // ---- T3: r[k5] -> (row (t&~3) + (k5>>2), col 4*(k5&3) + l2) ----
    {
        if (lo) {
            #pragma unroll
            for (int k = 0; k < 16; ++k)
                lds[((t & ~3) + (k >> 2)) * LDS_PITCH + 4*(k & 3) + l2] = r[k];
        }
        __syncthreads();
        if (lo) {
            #pragma unroll
            for (int j = 0; j < 16; ++j) r[j] = lds[tr * LDS_PITCH + j];
        }
        __syncthreads();
        if (!lo) {
            #pragma unroll
            for (int k = 0; k < 16; ++k)
                lds[((tr & ~3) + (k >> 2)) * LDS_PITCH + 4*(k & 3) + l2] = r[k];
        }
        __syncthreads();
        if (!lo) {
            #pragma unroll
            for (int j = 0; j < 16; ++j) r[j] = lds[tr * LDS_PITCH + j];
        }
        __syncthreads();
    }

    // ---- P4: DFT-4 over b3 within each k5l group ----
    #pragma unroll
    for (int q = 0; q < 4; ++q)
        dft4_t<-1>(r[4*q], r[4*q+1], r[4*q+2], r[4*q+3]);

    // ---- pointwise multiply by pre-permuted Hermitian kernel ----
    {
        const float4* kp4 = (const float4*)(kperm + t * 16);
        float4 kv[8];
        #pragma unroll
        for (int i = 0; i < 8; ++i) kv[i] = kp4[i];
        #pragma unroll
        for (int i = 0; i < 8; ++i) {
            r[2*i]   = cmul(r[2*i],   make_float2(kv[i].x, kv[i].y));
            r[2*i+1] = cmul(r[2*i+1], make_float2(kv[i].z, kv[i].w));
        }
    }

    // ---- IP4: inverse DFT-4 over k6 ----
    #pragma unroll
    for (int q = 0; q < 4; ++q)
        dft4_t<1>(r[4*q], r[4*q+1], r[4*q+2], r[4*q+3]);

    // ---- IT3: r[4*k5l+b3] -> (row (t&~3)+b3, col (4*l2 + k5l) ^ h) ----
    {
        if (lo) {
            #pragma unroll
            for (int j = 0; j < 16; ++j)
                lds[((t & ~3) + (j & 3)) * LDS_PITCH + ((4*l2 + (j >> 2)) ^ h)] = r[j];
        }
        __syncthreads();
        if (lo) {
            #pragma unroll
            for (int k = 0; k < 16; ++k) r[k] = lds[tr * LDS_PITCH + (k ^ h)];
        }
        __syncthreads();
        if (!lo) {
            #pragma unroll
            for (int j = 0; j < 16; ++j)
                lds[((tr & ~3) + (j & 3)) * LDS_PITCH + ((4*l2 + (j >> 2)) ^ h)] = r[j];
        }
        __syncthreads();
        if (!lo) {
            #pragma unroll
            for (int k = 0; k < 16; ++k) r[k] = lds[tr * LDS_PITCH + (k ^ h)];
        }
        __syncthreads();
    }

    // ---- IP3: conj twiddle W_64, inverse DFT-16 over k5 ----
    {
        float2 ww = twid[256 * l2];
        twiddle15(r, make_float2(ww.x, -ww.y));
    }
    dft16_t<1>(r);

    // ---- IT2: r[a3] -> (row w*64 + l2 + 4*a3, col h); read (row t, col k) ----
    {
        if (lo) {
            #pragma unroll
            for (int a = 0; a < 16; ++a)
                lds[(w*64 + l2 + 4*a) * LDS_PITCH + h] = r[a];
        }
        __syncthreads();
        if (lo) {
            #pragma unroll
            for (int k = 0; k < 16; ++k) r[k] = lds[tr * LDS_PITCH + k];
        }
        __syncthreads();
        if (!lo) {
            #pragma unroll
            for (int a = 0; a < 16; ++a)
                lds[((w & 7)*64 + l2 + 4*a) * LDS_PITCH + h] = r[a];
        }
        __syncthreads();
        if (!lo) {
            #pragma unroll
            for (int k = 0; k < 16; ++k) r[k] = lds[tr * LDS_PITCH + k];
        }
        __syncthreads();
    }

    // ---- IP2: conj twiddle W_1024, inverse DFT-16 over k3 ----
    {
        float2 ww = twid[16 * lane];
        twiddle15(r, make_float2(ww.x, -ww.y));
    }
    dft16_t<1>(r);

    // ---- IT1: r[a2] -> (row lane + 64*a2, col w); read (row t, col k) ----
    {
        #pragma unroll
        for (int a = 0; a < 8; ++a)
            lds[(lane + 64*a) * LDS_PITCH + w] = r[a];
        __syncthreads();
        float2 tmp[16];
        if (lo) {
            #pragma unroll
            for (int k = 0; k < 16; ++k) tmp[k] = lds[tr * LDS_PITCH + k];
        }
        __syncthreads();
        #pragma unroll
        for (int a = 8; a < 16; ++a)
            lds[(lane + 64*(a - 8)) * LDS_PITCH + w] = r[a];
        __syncthreads();
        if (!lo) {
            #pragma unroll
            for (int k = 0; k < 16; ++k) tmp[k] = lds[tr * LDS_PITCH + k];
        }
        #pragma unroll
        for (int k = 0; k < 16; ++k) r[k] = tmp[k];
    }

    // ---- IP1: conj twiddle W_16384, inverse DFT-16 over k1 ----
    {
        float2 ww = twid[t];
        twiddle15(r, make_float2(ww.x, -ww.y));
    }
    dft16_t<1>(r);

    // ---- store: Re -> row0, Im -> row1 (coalesced) ----
    float* y0 = y + rowbase;
    float* y1 = y0 + LFFT;
    #pragma unroll
    for (int a = 0; a < 16; ++a) {
        y0[t + NTHREADS*a] = r[a].x;
        y1[t + NTHREADS*a] = r[a].y;
    }
}

extern "C" void kernel_launch(void* const* d_in, const int* in_sizes, int n_in,
                              void* d_out, int out_size, void* d_ws, size_t ws_size,
                              hipStream_t stream)
{
    const float* x  = (const float*)d_in[0];
    const float* Lr = (const float*)d_in[1];
    const float* Li = (const float*)d_in[2];
    const float* Pr = (const float*)d_in[3];
    const float* Pi = (const float*)d_in[4];
    const float* Br = (const float*)d_in[5];
    const float* Bi = (const float*)d_in[6];
    const float* Cr = (const float*)d_in[7];
    const float* Ci = (const float*)d_in[8];
    const float* st = (const float*)d_in[9];

    const int rows = in_sizes[0] / LFFT;   // 1024

    float2* twid  = (float2*)d_ws;          // LFFT float2
    float2* Kperm = twid + LFFT;            // LFFT float2

    s4_tables<<<LFFT / 256, 256, 0, stream>>>(Lr, Li, Pr, Pi, Br, Bi, Cr, Ci, st,
                                              Kperm, twid);
    fft_conv<<<rows / 2, NTHREADS, 0, stream>>>(x, (float*)d_out, twid, Kperm);
}

// Round 4
// 104.219 us; speedup vs baseline: 1.7504x; 1.7504x over previous
//
#include <hip/hip_runtime.h>
#include <math.h>

#define LFFT 16384
#define NTHREADS 1024
#define LDS_PITCH 17   // float2 per row (16 + 1 pad)

__device__ __forceinline__ float2 cadd(float2 a, float2 b){ return make_float2(a.x+b.x, a.y+b.y); }
__device__ __forceinline__ float2 csub(float2 a, float2 b){ return make_float2(a.x-b.x, a.y-b.y); }
__device__ __forceinline__ float2 cmul(float2 a, float2 b){ return make_float2(a.x*b.x - a.y*b.y, a.x*b.y + a.y*b.x); }

template<int S> __device__ __forceinline__ float2 mul_is(float2 a) {
    return make_float2(-(float)S * a.y, (float)S * a.x);
}

// Radix-4 butterfly. S=-1 fwd, S=+1 inverse (unnormalized).
template<int S> __device__ __forceinline__ void dft4_t(float2& a0, float2& a1, float2& a2, float2& a3) {
    float2 t0 = cadd(a0, a2);
    float2 t1 = csub(a0, a2);
    float2 t2 = cadd(a1, a3);
    float2 t3 = csub(a1, a3);
    a0 = cadd(t0, t2);
    a2 = csub(t0, t2);
    const float s = (float)S;
    a1 = make_float2(t1.x - s * t3.y, t1.y + s * t3.x);
    a3 = make_float2(t1.x + s * t3.y, t1.y - s * t3.x);
}

#define C16A 0.92387953251128675613f
#define C16B 0.70710678118654752440f
#define C16C 0.38268343236508977173f

// Fully-unrolled 16-point DFT, natural order in and out.
template<int S> __device__ __forceinline__ void dft16_t(float2 r[16]) {
    const float s = (float)S;
    const float2 w1 = make_float2( C16A, s * C16C);
    const float2 w2 = make_float2( C16B, s * C16B);
    const float2 w3 = make_float2( C16C, s * C16A);
    const float2 w6 = make_float2(-C16B, s * C16B);
    const float2 w9 = make_float2(-C16A, -s * C16C);
    float2 g[4][4];
    #pragma unroll
    for (int b = 0; b < 4; ++b) {
        float2 a0 = r[b], a1 = r[b+4], a2 = r[b+8], a3 = r[b+12];
        dft4_t<S>(a0, a1, a2, a3);
        g[b][0] = a0; g[b][1] = a1; g[b][2] = a2; g[b][3] = a3;
    }
    g[1][1] = cmul(g[1][1], w1);  g[1][2] = cmul(g[1][2], w2);  g[1][3] = cmul(g[1][3], w3);
    g[2][1] = cmul(g[2][1], w2);  g[2][2] = mul_is<S>(g[2][2]); g[2][3] = cmul(g[2][3], w6);
    g[3][1] = cmul(g[3][1], w3);  g[3][2] = cmul(g[3][2], w6);  g[3][3] = cmul(g[3][3], w9);
    #pragma unroll
    for (int ka = 0; ka < 4; ++ka) {
        float2 a0 = g[0][ka], a1 = g[1][ka], a2 = g[2][ka], a3 = g[3][ka];
        dft4_t<S>(a0, a1, a2, a3);
        r[ka] = a0; r[ka+4] = a1; r[ka+8] = a2; r[ka+12] = a3;
    }
}

// r[k] *= w^k, k = 1..15
__device__ __forceinline__ void twiddle15(float2 r[16], float2 w) {
    float2 w2 = cmul(w, w);
    float2 we = w2;
    float2 wo = cmul(w, w2);
    r[1] = cmul(r[1], w);
    r[2] = cmul(r[2], we);
    r[3] = cmul(r[3], wo);
    #pragma unroll
    for (int j = 2; j <= 7; ++j) {
        we = cmul(we, w2);  r[2*j]   = cmul(r[2*j],   we);
        wo = cmul(wo, w2);  r[2*j+1] = cmul(r[2*j+1], wo);
    }
}

// ---------------------------------------------------------------------------
// Kernel 1: one fp64 evaluation of the S4 generating function per thread at
// root-of-unity index m (natural order), plus the fp32 twiddle table.
// ---------------------------------------------------------------------------
__global__ void s4_eval(const float* __restrict__ Lr, const float* __restrict__ Li,
                        const float* __restrict__ Pr, const float* __restrict__ Pi,
                        const float* __restrict__ Br, const float* __restrict__ Bi,
                        const float* __restrict__ Cr, const float* __restrict__ Ci,
                        const float* __restrict__ step_ptr,
                        float2* __restrict__ Kraw, float2* __restrict__ twid)
{
    int m = blockIdx.x * blockDim.x + threadIdx.x;
    if (m >= LFFT) return;
    double theta = (-2.0 * M_PI / (double)LFFT) * (double)m;
    double si, co;
    sincos(theta, &si, &co);
    twid[m] = make_float2((float)co, (float)si);

    double step = (double)step_ptr[0];
    double opr = 1.0 + co, opi = si;   // 1 + Omega
    double omr = 1.0 - co, omi = -si;  // 1 - Omega
    double iden = 1.0 / (opr*opr + opi*opi);
    double gs = 2.0 / step;
    double gr = gs * (omr*opr + omi*opi) * iden;
    double gi = gs * (omi*opr - omr*opi) * iden;
    double cr = 2.0 * opr * iden;
    double ci = -2.0 * opi * iden;

    double k00r=0,k00i=0,k01r=0,k01i=0,k10r=0,k10i=0,k11r=0,k11i=0;
    for (int n = 0; n < 64; ++n) {
        double dr = gr - (double)Lr[n];
        double di = gi - (double)Li[n];
        double id2 = 1.0 / (dr*dr + di*di);
        double vr =  dr * id2;
        double vi = -di * id2;
        double a0r = (double)Cr[n], a0i = -(double)Ci[n];
        double a1r = (double)Pr[n], a1i = -(double)Pi[n];
        double br  = (double)Br[n], bi  = (double)Bi[n];
        double pr  = (double)Pr[n], pi  = (double)Pi[n];
        double e00r = a0r*br - a0i*bi, e00i = a0r*bi + a0i*br;
        double e01r = a0r*pr - a0i*pi, e01i = a0r*pi + a0i*pr;
        double e10r = a1r*br - a1i*bi, e10i = a1r*bi + a1i*br;
        double e11r = a1r*pr - a1i*pi, e11i = a1r*pi + a1i*pr;
        k00r += vr*e00r - vi*e00i;  k00i += vr*e00i + vi*e00r;
        k01r += vr*e01r - vi*e01i;  k01i += vr*e01i + vi*e01r;
        k10r += vr*e10r - vi*e10i;  k10i += vr*e10i + vi*e10r;
        k11r += vr*e11r - vi*e11i;  k11i += vr*e11i + vi*e11r;
    }
    double rr = 1.0 + k11r, ri = k11i;
    double ir2 = 1.0 / (rr*rr + ri*ri);
    double qr0 = k01r*k10r - k01i*k10i;
    double qi0 = k01r*k10i + k01i*k10r;
    double qr = (qr0*rr + qi0*ri) * ir2;
    double qi = (qi0*rr - qr0*ri) * ir2;
    double sr = k00r - qr, sim = k00i - qi;
    Kraw[m] = make_float2((float)(cr*sr - ci*sim), (float)(cr*sim + ci*sr));
}

// ---------------------------------------------------------------------------
// Kernel 2: Hermitian-symmetrize (Ktilde_k = (K_k + conj(K_{L-k}))/2), fold
// in 1/L, and store in the exact (thread t, slot j) order of the fft_conv
// multiply point:  p = t*16 + j ;
//   m = k1 + 16*k3 + 256*(4*k5h + k5l) + 4096*k6
//   k1=t>>6, k3=(t>>2)&15, k5h=t&3, k5l=j>>2, k6=j&3
// ---------------------------------------------------------------------------
__global__ void s4_perm(const float2* __restrict__ Kraw, float2* __restrict__ Kperm)
{
    int p = blockIdx.x * blockDim.x + threadIdx.x;
    if (p >= LFFT) return;
    int t = p >> 4, j = p & 15;
    int k1 = t >> 6, k3 = (t >> 2) & 15, k5h = t & 3;
    int k5l = j >> 2, k6 = j & 3;
    int m = k1 + 16*k3 + 256*(4*k5h + k5l) + 4096*k6;
    float2 a = Kraw[m];
    float2 b = Kraw[(LFFT - m) & (LFFT - 1)];
    const float s = 0.5f / (float)LFFT;
    Kperm[p] = make_float2(s * (a.x + b.x), s * (a.y - b.y));
}

// ---------------------------------------------------------------------------
// Full FFT -> multiply -> IFFT chain on one packed complex row held in r[16].
// Identical (verified) round-2 structure: four-step 16384 = 16x16x16x4,
// LDS transposes at pitch 17, writes scatter / reads read own row.
// ---------------------------------------------------------------------------
__device__ __forceinline__ void fft_chain(float2 (&r)[16], const int t,
    float2* __restrict__ lds, const float2* __restrict__ twid,
    const float2* __restrict__ kperm,
    float* __restrict__ y0, float* __restrict__ y1)
{
    const int lane = t & 63;
    const int w    = t >> 6;
    const int l2   = t & 3;
    const int h    = (t >> 2) & 15;

    // ---- P1: DFT-16 over a, twiddle W_16384^(t*k1) ----
    dft16_t<-1>(r);
    twiddle15(r, twid[t]);

    // ---- T1 ----
    #pragma unroll
    for (int k = 0; k < 16; ++k)
        lds[(k*64 + lane) * LDS_PITCH + w] = r[k];
    __syncthreads();
    #pragma unroll
    for (int a = 0; a < 16; ++a)
        r[a] = lds[t * LDS_PITCH + a];
    __syncthreads();

    // ---- P2 ----
    dft16_t<-1>(r);
    twiddle15(r, twid[16 * lane]);

    // ---- T2 ----
    #pragma unroll
    for (int k = 0; k < 16; ++k)
        lds[(w*64 + 4*k + l2) * LDS_PITCH + h] = r[k];
    __syncthreads();
    #pragma unroll
    for (int a = 0; a < 16; ++a)
        r[a] = lds[t * LDS_PITCH + a];
    __syncthreads();

    // ---- P3 ----
    dft16_t<-1>(r);
    twiddle15(r, twid[256 * l2]);

    // ---- T3 ----
    #pragma unroll
    for (int k = 0; k < 16; ++k)
        lds[((t & ~3) + (k >> 2)) * LDS_PITCH + 4*(k & 3) + l2] = r[k];
    __syncthreads();
    #pragma unroll
    for (int j = 0; j < 16; ++j)
        r[j] = lds[t * LDS_PITCH + j];
    __syncthreads();

    // ---- P4: DFT-4 over b3 ----
    #pragma unroll
    for (int q = 0; q < 4; ++q)
        dft4_t<-1>(r[4*q], r[4*q+1], r[4*q+2], r[4*q+3]);

    // ---- pointwise multiply (chunked to limit VGPR spike) ----
    {
        const float4* kp4 = (const float4*)(kperm + t * 16);
        #pragma unroll
        for (int c = 0; c < 2; ++c) {
            float4 kv[4];
            #pragma unroll
            for (int i = 0; i < 4; ++i) kv[i] = kp4[4*c + i];
            #pragma unroll
            for (int i = 0; i < 4; ++i) {
                r[8*c + 2*i]     = cmul(r[8*c + 2*i],     make_float2(kv[i].x, kv[i].y));
                r[8*c + 2*i + 1] = cmul(r[8*c + 2*i + 1], make_float2(kv[i].z, kv[i].w));
            }
        }
    }

    // ---- IP4 ----
    #pragma unroll
    for (int q = 0; q < 4; ++q)
        dft4_t<1>(r[4*q], r[4*q+1], r[4*q+2], r[4*q+3]);

    // ---- IT3 ----
    #pragma unroll
    for (int j = 0; j < 16; ++j)
        lds[((t & ~3) + (j & 3)) * LDS_PITCH + ((4*l2 + (j >> 2)) ^ h)] = r[j];
    __syncthreads();
    #pragma unroll
    for (int k = 0; k < 16; ++k)
        r[k] = lds[t * LDS_PITCH + (k ^ h)];
    __syncthreads();

    // ---- IP3 ----
    { float2 ww = twid[256 * l2]; twiddle15(r, make_float2(ww.x, -ww.y)); }
    dft16_t<1>(r);

    // ---- IT2 ----
    #pragma unroll
    for (int a = 0; a < 16; ++a)
        lds[(w*64 + l2 + 4*a) * LDS_PITCH + h] = r[a];
    __syncthreads();
    #pragma unroll
    for (int k = 0; k < 16; ++k)
        r[k] = lds[t * LDS_PITCH + k];
    __syncthreads();

    // ---- IP2 ----
    { float2 ww = twid[16 * lane]; twiddle15(r, make_float2(ww.x, -ww.y)); }
    dft16_t<1>(r);

    // ---- IT1 ----
    #pragma unroll
    for (int a = 0; a < 16; ++a)
        lds[(lane + 64*a) * LDS_PITCH + w] = r[a];
    __syncthreads();
    #pragma unroll
    for (int k = 0; k < 16; ++k)
        r[k] = lds[t * LDS_PITCH + k];

    // ---- IP1 ----
    { float2 ww = twid[t]; twiddle15(r, make_float2(ww.x, -ww.y)); }
    dft16_t<1>(r);

    // ---- store (coalesced) ----
    #pragma unroll
    for (int a = 0; a < 16; ++a) {
        y0[t + NTHREADS*a] = r[a].x;
        y1[t + NTHREADS*a] = r[a].y;
    }
}

// ---------------------------------------------------------------------------
// Kernel 3: persistent blocks, two row-pairs per block. Pair-B's global
// loads are issued up front (32 spare VGPRs) so they're in flight during
// pair-A's entire compute; pair-A's stores drain under pair-B's compute.
// ---------------------------------------------------------------------------
__global__ __launch_bounds__(NTHREADS, 4) void fft_conv(
    const float* __restrict__ x, float* __restrict__ y,
    const float2* __restrict__ twid, const float2* __restrict__ kperm)
{
    __shared__ float2 lds[NTHREADS * LDS_PITCH];   // 136 KiB
    const int t = threadIdx.x;
    const size_t base0 = (size_t)blockIdx.x * 2u * LFFT;
    const size_t base1 = ((size_t)blockIdx.x + gridDim.x) * 2u * LFFT;
    const float* x0 = x + base0;
    const float* x1 = x0 + LFFT;
    const float* x2 = x + base1;
    const float* x3 = x2 + LFFT;

    float2 r[16], p[16];
    #pragma unroll
    for (int a = 0; a < 16; ++a)
        r[a] = make_float2(x0[t + NTHREADS*a], x1[t + NTHREADS*a]);
    #pragma unroll
    for (int a = 0; a < 16; ++a)
        p[a] = make_float2(x2[t + NTHREADS*a], x3[t + NTHREADS*a]);

    fft_chain(r, t, lds, twid, kperm, y + base0, y + base0 + LFFT);
    __syncthreads();   // all IT1 reads of pair A done before pair B's T1 writes
    fft_chain(p, t, lds, twid, kperm, y + base1, y + base1 + LFFT);
}

extern "C" void kernel_launch(void* const* d_in, const int* in_sizes, int n_in,
                              void* d_out, int out_size, void* d_ws, size_t ws_size,
                              hipStream_t stream)
{
    const float* x  = (const float*)d_in[0];
    const float* Lr = (const float*)d_in[1];
    const float* Li = (const float*)d_in[2];
    const float* Pr = (const float*)d_in[3];
    const float* Pi = (const float*)d_in[4];
    const float* Br = (const float*)d_in[5];
    const float* Bi = (const float*)d_in[6];
    const float* Cr = (const float*)d_in[7];
    const float* Ci = (const float*)d_in[8];
    const float* st = (const float*)d_in[9];

    const int rows   = in_sizes[0] / LFFT;  // 1024
    const int pairs  = rows / 2;            // 512
    const int blocks = pairs / 2;           // 256 persistent blocks

    float2* twid  = (float2*)d_ws;          // LFFT float2
    float2* Kraw  = twid + LFFT;            // LFFT float2
    float2* Kperm = Kraw + LFFT;            // LFFT float2

    s4_eval<<<LFFT / 256, 256, 0, stream>>>(Lr, Li, Pr, Pi, Br, Bi, Cr, Ci, st,
                                            Kraw, twid);
    s4_perm<<<LFFT / 256, 256, 0, stream>>>(Kraw, Kperm);
    fft_conv<<<blocks, NTHREADS, 0, stream>>>(x, (float*)d_out, twid, Kperm);
}

// Round 5
// 74.004 us; speedup vs baseline: 2.4651x; 1.4083x over previous
//
#include <hip/hip_runtime.h>
#include <math.h>

#define LFFT 16384
#define NTHREADS 1024
#define LDS_PITCH 17   // float2 per row (16 + 1 pad)

// Wave-local LDS ordering: all my outstanding DS ops complete before any
// later DS op issues. Compiler motion blocked by the "memory" clobber.
#define LDS_FENCE() asm volatile("s_waitcnt lgkmcnt(0)" ::: "memory")

__device__ __forceinline__ float2 cadd(float2 a, float2 b){ return make_float2(a.x+b.x, a.y+b.y); }
__device__ __forceinline__ float2 csub(float2 a, float2 b){ return make_float2(a.x-b.x, a.y-b.y); }
__device__ __forceinline__ float2 cmul(float2 a, float2 b){ return make_float2(a.x*b.x - a.y*b.y, a.x*b.y + a.y*b.x); }

template<int S> __device__ __forceinline__ float2 mul_is(float2 a) {
    return make_float2(-(float)S * a.y, (float)S * a.x);
}

// Radix-4 butterfly. S=-1 fwd, S=+1 inverse (unnormalized).
template<int S> __device__ __forceinline__ void dft4_t(float2& a0, float2& a1, float2& a2, float2& a3) {
    float2 t0 = cadd(a0, a2);
    float2 t1 = csub(a0, a2);
    float2 t2 = cadd(a1, a3);
    float2 t3 = csub(a1, a3);
    a0 = cadd(t0, t2);
    a2 = csub(t0, t2);
    const float s = (float)S;
    a1 = make_float2(t1.x - s * t3.y, t1.y + s * t3.x);
    a3 = make_float2(t1.x + s * t3.y, t1.y - s * t3.x);
}

#define C16A 0.92387953251128675613f
#define C16B 0.70710678118654752440f
#define C16C 0.38268343236508977173f

// Fully-unrolled 16-point DFT, natural order in and out.
template<int S> __device__ __forceinline__ void dft16_t(float2 r[16]) {
    const float s = (float)S;
    const float2 w1 = make_float2( C16A, s * C16C);
    const float2 w2 = make_float2( C16B, s * C16B);
    const float2 w3 = make_float2( C16C, s * C16A);
    const float2 w6 = make_float2(-C16B, s * C16B);
    const float2 w9 = make_float2(-C16A, -s * C16C);
    float2 g[4][4];
    #pragma unroll
    for (int b = 0; b < 4; ++b) {
        float2 a0 = r[b], a1 = r[b+4], a2 = r[b+8], a3 = r[b+12];
        dft4_t<S>(a0, a1, a2, a3);
        g[b][0] = a0; g[b][1] = a1; g[b][2] = a2; g[b][3] = a3;
    }
    g[1][1] = cmul(g[1][1], w1);  g[1][2] = cmul(g[1][2], w2);  g[1][3] = cmul(g[1][3], w3);
    g[2][1] = cmul(g[2][1], w2);  g[2][2] = mul_is<S>(g[2][2]); g[2][3] = cmul(g[2][3], w6);
    g[3][1] = cmul(g[3][1], w3);  g[3][2] = cmul(g[3][2], w6);  g[3][3] = cmul(g[3][3], w9);
    #pragma unroll
    for (int ka = 0; ka < 4; ++ka) {
        float2 a0 = g[0][ka], a1 = g[1][ka], a2 = g[2][ka], a3 = g[3][ka];
        dft4_t<S>(a0, a1, a2, a3);
        r[ka] = a0; r[ka+4] = a1; r[ka+8] = a2; r[ka+12] = a3;
    }
}

// r[k] *= w^k, k = 1..15
__device__ __forceinline__ void twiddle15(float2 r[16], float2 w) {
    float2 w2 = cmul(w, w);
    float2 we = w2;
    float2 wo = cmul(w, w2);
    r[1] = cmul(r[1], w);
    r[2] = cmul(r[2], we);
    r[3] = cmul(r[3], wo);
    #pragma unroll
    for (int j = 2; j <= 7; ++j) {
        we = cmul(we, w2);  r[2*j]   = cmul(r[2*j],   we);
        wo = cmul(wo, w2);  r[2*j+1] = cmul(r[2*j+1], wo);
    }
}

// ---------------------------------------------------------------------------
// Kernel 1: one fp64 evaluation of the S4 generating function per thread at
// root-of-unity index m (natural order), plus the fp32 twiddle table.
// ---------------------------------------------------------------------------
__global__ void s4_eval(const float* __restrict__ Lr, const float* __restrict__ Li,
                        const float* __restrict__ Pr, const float* __restrict__ Pi,
                        const float* __restrict__ Br, const float* __restrict__ Bi,
                        const float* __restrict__ Cr, const float* __restrict__ Ci,
                        const float* __restrict__ step_ptr,
                        float2* __restrict__ Kraw, float2* __restrict__ twid)
{
    int m = blockIdx.x * blockDim.x + threadIdx.x;
    if (m >= LFFT) return;
    double theta = (-2.0 * M_PI / (double)LFFT) * (double)m;
    double si, co;
    sincos(theta, &si, &co);
    twid[m] = make_float2((float)co, (float)si);

    double step = (double)step_ptr[0];
    double opr = 1.0 + co, opi = si;   // 1 + Omega
    double omr = 1.0 - co, omi = -si;  // 1 - Omega
    double iden = 1.0 / (opr*opr + opi*opi);
    double gs = 2.0 / step;
    double gr = gs * (omr*opr + omi*opi) * iden;
    double gi = gs * (omi*opr - omr*opi) * iden;
    double cr = 2.0 * opr * iden;
    double ci = -2.0 * opi * iden;

    double k00r=0,k00i=0,k01r=0,k01i=0,k10r=0,k10i=0,k11r=0,k11i=0;
    for (int n = 0; n < 64; ++n) {
        double dr = gr - (double)Lr[n];
        double di = gi - (double)Li[n];
        double id2 = 1.0 / (dr*dr + di*di);
        double vr =  dr * id2;
        double vi = -di * id2;
        double a0r = (double)Cr[n], a0i = -(double)Ci[n];
        double a1r = (double)Pr[n], a1i = -(double)Pi[n];
        double br  = (double)Br[n], bi  = (double)Bi[n];
        double pr  = (double)Pr[n], pi  = (double)Pi[n];
        double e00r = a0r*br - a0i*bi, e00i = a0r*bi + a0i*br;
        double e01r = a0r*pr - a0i*pi, e01i = a0r*pi + a0i*pr;
        double e10r = a1r*br - a1i*bi, e10i = a1r*bi + a1i*br;
        double e11r = a1r*pr - a1i*pi, e11i = a1r*pi + a1i*pr;
        k00r += vr*e00r - vi*e00i;  k00i += vr*e00i + vi*e00r;
        k01r += vr*e01r - vi*e01i;  k01i += vr*e01i + vi*e01r;
        k10r += vr*e10r - vi*e10i;  k10i += vr*e10i + vi*e10r;
        k11r += vr*e11r - vi*e11i;  k11i += vr*e11i + vi*e11r;
    }
    double rr = 1.0 + k11r, ri = k11i;
    double ir2 = 1.0 / (rr*rr + ri*ri);
    double qr0 = k01r*k10r - k01i*k10i;
    double qi0 = k01r*k10i + k01i*k10r;
    double qr = (qr0*rr + qi0*ri) * ir2;
    double qi = (qi0*rr - qr0*ri) * ir2;
    double sr = k00r - qr, sim = k00i - qi;
    Kraw[m] = make_float2((float)(cr*sr - ci*sim), (float)(cr*sim + ci*sr));
}

// ---------------------------------------------------------------------------
// Kernel 2: Hermitian-symmetrize, fold in 1/L, store in the fft_conv
// (thread t, slot j) multiply order:
//   p = t*16 + j ; m = k1 + 16*k3 + 256*(4*k5h + k5l) + 4096*k6
//   k1=t>>6, k3=(t>>2)&15, k5h=t&3, k5l=j>>2, k6=j&3
// ---------------------------------------------------------------------------
__global__ void s4_perm(const float2* __restrict__ Kraw, float2* __restrict__ Kperm)
{
    int p = blockIdx.x * blockDim.x + threadIdx.x;
    if (p >= LFFT) return;
    int t = p >> 4, j = p & 15;
    int k1 = t >> 6, k3 = (t >> 2) & 15, k5h = t & 3;
    int k5l = j >> 2, k6 = j & 3;
    int m = k1 + 16*k3 + 256*(4*k5h + k5l) + 4096*k6;
    float2 a = Kraw[m];
    float2 b = Kraw[(LFFT - m) & (LFFT - 1)];
    const float s = 0.5f / (float)LFFT;
    Kperm[p] = make_float2(s * (a.x + b.x), s * (a.y - b.y));
}

// ---------------------------------------------------------------------------
// Kernel 3: register-resident four-step FFT/IFFT (16384 = 16x16x16x4),
// addressing identical to the verified round-2 kernel. Barrier analysis:
// T2/T3/IT3/IT2 move data only within each wave's own 64-row stripe
// (row ranges [64*(t>>6), 64*(t>>6)+64) for both writes and reads), so they
// need only a wave-local lgkmcnt fence, not __syncthreads(). Only T1 and
// IT1 (row = 64k+lane / lane+64a: stripe index = register index, written by
// every wave) are cross-wave. 3 workgroup barriers total (was 12) -> waves
// slip and overlap VALU with LDS phases naturally.
// ---------------------------------------------------------------------------
__global__ __launch_bounds__(NTHREADS, 4) void fft_conv(
    const float* __restrict__ x, float* __restrict__ y,
    const float2* __restrict__ twid, const float2* __restrict__ kperm)
{
    __shared__ float2 lds[NTHREADS * LDS_PITCH];   // 136 KiB
    const int t    = threadIdx.x;
    const int lane = t & 63;
    const int w    = t >> 6;
    const int l2   = t & 3;
    const int h    = (t >> 2) & 15;
    const size_t rowbase = (size_t)blockIdx.x * 2u * LFFT;
    const float* x0 = x + rowbase;
    const float* x1 = x0 + LFFT;

    float2 r[16];

    // ---- load: thread t owns n = t + 1024*a (coalesced) ----
    #pragma unroll
    for (int a = 0; a < 16; ++a)
        r[a] = make_float2(x0[t + NTHREADS*a], x1[t + NTHREADS*a]);

    // ---- P1: DFT-16 over a, twiddle W_16384^(t*k1) ----
    dft16_t<-1>(r);
    twiddle15(r, twid[t]);

    // ---- T1 (cross-wave): r[k] -> (row 64k+lane, col w); read own row ----
    #pragma unroll
    for (int k = 0; k < 16; ++k)
        lds[(k*64 + lane) * LDS_PITCH + w] = r[k];
    __syncthreads();
    #pragma unroll
    for (int a = 0; a < 16; ++a)
        r[a] = lds[t * LDS_PITCH + a];
    LDS_FENCE();   // my reads done before my T2 writes (same stripe)

    // ---- P2: DFT-16 over a2, twiddle W_1024^(lane*k3) ----
    dft16_t<-1>(r);
    twiddle15(r, twid[16 * lane]);

    // ---- T2 (wave-local stripe) ----
    #pragma unroll
    for (int k = 0; k < 16; ++k)
        lds[(w*64 + 4*k + l2) * LDS_PITCH + h] = r[k];
    LDS_FENCE();
    #pragma unroll
    for (int a = 0; a < 16; ++a)
        r[a] = lds[t * LDS_PITCH + a];
    LDS_FENCE();

    // ---- P3: DFT-16 over a3, twiddle W_64^(l2*k5) ----
    dft16_t<-1>(r);
    twiddle15(r, twid[256 * l2]);

    // ---- T3 (wave-local stripe) ----
    #pragma unroll
    for (int k = 0; k < 16; ++k)
        lds[((t & ~3) + (k >> 2)) * LDS_PITCH + 4*(k & 3) + l2] = r[k];
    LDS_FENCE();
    #pragma unroll
    for (int j = 0; j < 16; ++j)
        r[j] = lds[t * LDS_PITCH + j];
    LDS_FENCE();

    // ---- P4: DFT-4 over b3 ----
    #pragma unroll
    for (int q = 0; q < 4; ++q)
        dft4_t<-1>(r[4*q], r[4*q+1], r[4*q+2], r[4*q+3]);

    // ---- pointwise multiply (chunked) ----
    {
        const float4* kp4 = (const float4*)(kperm + t * 16);
        #pragma unroll
        for (int c = 0; c < 2; ++c) {
            float4 kv[4];
            #pragma unroll
            for (int i = 0; i < 4; ++i) kv[i] = kp4[4*c + i];
            #pragma unroll
            for (int i = 0; i < 4; ++i) {
                r[8*c + 2*i]     = cmul(r[8*c + 2*i],     make_float2(kv[i].x, kv[i].y));
                r[8*c + 2*i + 1] = cmul(r[8*c + 2*i + 1], make_float2(kv[i].z, kv[i].w));
            }
        }
    }

    // ---- IP4: inverse DFT-4 over k6 ----
    #pragma unroll
    for (int q = 0; q < 4; ++q)
        dft4_t<1>(r[4*q], r[4*q+1], r[4*q+2], r[4*q+3]);

    // ---- IT3 (wave-local stripe) ----
    #pragma unroll
    for (int j = 0; j < 16; ++j)
        lds[((t & ~3) + (j & 3)) * LDS_PITCH + ((4*l2 + (j >> 2)) ^ h)] = r[j];
    LDS_FENCE();
    #pragma unroll
    for (int k = 0; k < 16; ++k)
        r[k] = lds[t * LDS_PITCH + (k ^ h)];
    LDS_FENCE();

    // ---- IP3 ----
    { float2 ww = twid[256 * l2]; twiddle15(r, make_float2(ww.x, -ww.y)); }
    dft16_t<1>(r);

    // ---- IT2 (wave-local stripe) ----
    #pragma unroll
    for (int a = 0; a < 16; ++a)
        lds[(w*64 + l2 + 4*a) * LDS_PITCH + h] = r[a];
    LDS_FENCE();
    #pragma unroll
    for (int k = 0; k < 16; ++k)
        r[k] = lds[t * LDS_PITCH + k];

    // ---- IP2 ----
    { float2 ww = twid[16 * lane]; twiddle15(r, make_float2(ww.x, -ww.y)); }
    dft16_t<1>(r);

    // ---- IT1 (cross-wave): wait all waves' IT2 reads, then exchange ----
    __syncthreads();
    #pragma unroll
    for (int a = 0; a < 16; ++a)
        lds[(lane + 64*a) * LDS_PITCH + w] = r[a];
    __syncthreads();
    #pragma unroll
    for (int k = 0; k < 16; ++k)
        r[k] = lds[t * LDS_PITCH + k];

    // ---- IP1 ----
    { float2 ww = twid[t]; twiddle15(r, make_float2(ww.x, -ww.y)); }
    dft16_t<1>(r);

    // ---- store: Re -> row0, Im -> row1 (coalesced) ----
    float* y0 = y + rowbase;
    float* y1 = y0 + LFFT;
    #pragma unroll
    for (int a = 0; a < 16; ++a) {
        y0[t + NTHREADS*a] = r[a].x;
        y1[t + NTHREADS*a] = r[a].y;
    }
}

extern "C" void kernel_launch(void* const* d_in, const int* in_sizes, int n_in,
                              void* d_out, int out_size, void* d_ws, size_t ws_size,
                              hipStream_t stream)
{
    const float* x  = (const float*)d_in[0];
    const float* Lr = (const float*)d_in[1];
    const float* Li = (const float*)d_in[2];
    const float* Pr = (const float*)d_in[3];
    const float* Pi = (const float*)d_in[4];
    const float* Br = (const float*)d_in[5];
    const float* Bi = (const float*)d_in[6];
    const float* Cr = (const float*)d_in[7];
    const float* Ci = (const float*)d_in[8];
    const float* st = (const float*)d_in[9];

    const int rows = in_sizes[0] / LFFT;   // 1024

    float2* twid  = (float2*)d_ws;          // LFFT float2
    float2* Kraw  = twid + LFFT;            // LFFT float2
    float2* Kperm = Kraw + LFFT;            // LFFT float2

    s4_eval<<<LFFT / 256, 256, 0, stream>>>(Lr, Li, Pr, Pi, Br, Bi, Cr, Ci, st,
                                            Kraw, twid);
    s4_perm<<<LFFT / 256, 256, 0, stream>>>(Kraw, Kperm);
    fft_conv<<<rows / 2, NTHREADS, 0, stream>>>(x, (float*)d_out, twid, Kperm);
}